// Round 3
// baseline (783.395 us; speedup 1.0000x reference)
//
#include <hip/hip_runtime.h>
#include <hip/hip_bf16.h>
#include <cstdint>

typedef unsigned short u16;
typedef __bf16 v8bf __attribute__((ext_vector_type(8)));
typedef short v4s __attribute__((ext_vector_type(4)));
typedef float v4f __attribute__((ext_vector_type(4)));

__device__ __forceinline__ u16 f2bf(float f) {
  union { float f; uint32_t u; } v; v.f = f;
  return (u16)((v.u + 0x7fffu + ((v.u >> 16) & 1u)) >> 16);
}

// async global->LDS, 16B per lane; LDS dest = wave-uniform base + lane*16
#define GLL16(gsrc, ldst) \
  __builtin_amdgcn_global_load_lds((__attribute__((address_space(1))) void*)(gsrc), \
      (__attribute__((address_space(3))) void*)(ldst), 16, 0, 0)

// ---------------- batched LayerNorm: 4x (fp32 row -> bf16 row) ----------------
struct LnBatch {
  const float* x[4]; const float* g[4]; const float* b[4]; u16* o[4];
};
__global__ __launch_bounds__(256) void ln_batch_kernel(LnBatch P)
{
  int id = blockIdx.x >> 13;           // 8192 rows per sub-LN
  int row = blockIdx.x & 8191, tid = threadIdx.x;
  const float4* xr = (const float4*)(P.x[id] + (size_t)row * 1024);
  float4 v = xr[tid];
  float s = v.x + v.y + v.z + v.w;
  float ss = v.x*v.x + v.y*v.y + v.z*v.z + v.w*v.w;
  for (int d = 1; d < 64; d <<= 1) { s += __shfl_xor(s, d); ss += __shfl_xor(ss, d); }
  __shared__ float red[8];
  int wv = tid >> 6, lane = tid & 63;
  if (lane == 0) { red[wv] = s; red[4 + wv] = ss; }
  __syncthreads();
  s  = red[0] + red[1] + red[2] + red[3];
  ss = red[4] + red[5] + red[6] + red[7];
  float mean = s * (1.f/1024.f);
  float var  = ss * (1.f/1024.f) - mean*mean;
  float rs = rsqrtf(var + 1e-5f);
  float4 gv = ((const float4*)P.g[id])[tid];
  float4 bv = ((const float4*)P.b[id])[tid];
  ushort4 o;
  o.x = f2bf((v.x-mean)*rs*gv.x + bv.x);
  o.y = f2bf((v.y-mean)*rs*gv.y + bv.y);
  o.z = f2bf((v.z-mean)*rs*gv.z + bv.z);
  o.w = f2bf((v.w-mean)*rs*gv.w + bv.w);
  ((ushort4*)P.o[id])[(size_t)row*256 + tid] = o;
}

// ---------------- fused x1 + o1 + o2 -> d_out(fp32) and LN -> bf16 ----------------
__global__ __launch_bounds__(256) void addln_kernel(
    const float* __restrict__ x1, const float* __restrict__ o1, const float* __restrict__ o2,
    const float* __restrict__ g, const float* __restrict__ bt,
    float* __restrict__ xsum, u16* __restrict__ out)
{
  int row = blockIdx.x, tid = threadIdx.x;
  size_t base = (size_t)row * 256 + tid;
  float4 v  = ((const float4*)x1)[base];
  float4 a  = ((const float4*)o1)[base];
  float4 b2 = ((const float4*)o2)[base];
  v.x += a.x + b2.x; v.y += a.y + b2.y; v.z += a.z + b2.z; v.w += a.w + b2.w;
  ((float4*)xsum)[base] = v;
  float s = v.x + v.y + v.z + v.w;
  float ss = v.x*v.x + v.y*v.y + v.z*v.z + v.w*v.w;
  for (int d = 1; d < 64; d <<= 1) { s += __shfl_xor(s, d); ss += __shfl_xor(ss, d); }
  __shared__ float red[8];
  int wv = tid >> 6, lane = tid & 63;
  if (lane == 0) { red[wv] = s; red[4 + wv] = ss; }
  __syncthreads();
  s  = red[0] + red[1] + red[2] + red[3];
  ss = red[4] + red[5] + red[6] + red[7];
  float mean = s * (1.f/1024.f);
  float var  = ss * (1.f/1024.f) - mean*mean;
  float rs = rsqrtf(var + 1e-5f);
  float4 gv = ((const float4*)g)[tid];
  float4 bv = ((const float4*)bt)[tid];
  ushort4 o;
  o.x = f2bf((v.x-mean)*rs*gv.x + bv.x);
  o.y = f2bf((v.y-mean)*rs*gv.y + bv.y);
  o.z = f2bf((v.z-mean)*rs*gv.z + bv.z);
  o.w = f2bf((v.w-mean)*rs*gv.w + bv.w);
  ((ushort4*)out)[base] = o;
}

// ------------- batched weight transpose+cast: W[K][N] -> WT[N][K] -------------
struct TDesc { const float* W; u16* WT; int K, N, tstart; };
struct TBatch { TDesc d[10]; };
__global__ __launch_bounds__(256) void transpose_batch(TBatch P)
{
  __shared__ float t[32][33];
  int bi = blockIdx.x;
  int idx = 0;
  #pragma unroll
  for (int i = 1; i < 10; ++i) if (bi >= P.d[i].tstart) idx = i;
  const float* W = P.d[idx].W;
  u16* WT = P.d[idx].WT;
  int K = P.d[idx].K, N = P.d[idx].N;
  int loc = bi - P.d[idx].tstart;
  int tiles_n = N >> 5;
  int bn = loc % tiles_n, bk = loc / tiles_n;
  int tx = threadIdx.x & 31, ty = threadIdx.x >> 5;
  #pragma unroll
  for (int j = 0; j < 4; ++j)
    t[ty + j*8][tx] = W[(size_t)(bk*32 + ty + j*8) * N + bn*32 + tx];
  __syncthreads();
  #pragma unroll
  for (int j = 0; j < 4; ++j)
    WT[(size_t)(bn*32 + ty + j*8) * K + bk*32 + tx] = f2bf(t[tx][ty + j*8]);
}

// ---------------- GEMM core (128x128 tile, BK=64, XOR-swizzled LDS) ----------------
// loads A[M,K], Bt[N,K]; accumulates acc[4][4]
#define GEMM_BODY(Aptr, Btptr, Kdim) \
  for (int kt = 0; kt < (Kdim); kt += 64) { \
    __syncthreads(); \
    _Pragma("unroll") \
    for (int c0 = 0; c0 < 4; ++c0) { \
      int chunk = wv*4 + c0; \
      int off = chunk*1024 + lane*16; \
      int row = off >> 7; \
      int sc  = (off >> 4) & 7; \
      int lg  = sc ^ (row & 7); \
      const u16* ga = (Aptr)  + (size_t)(bm*128 + row) * (Kdim) + kt + lg*8; \
      GLL16(ga, la + chunk*1024); \
      const u16* gb = (Btptr) + (size_t)(bn*128 + row) * (Kdim) + kt + lg*8; \
      GLL16(gb, lb + chunk*1024); \
    } \
    __syncthreads(); \
    _Pragma("unroll") \
    for (int kc = 0; kc < 2; ++kc) { \
      v8bf af[4], bfr[4]; \
      _Pragma("unroll") \
      for (int r = 0; r < 4; ++r) { \
        int row = wm*64 + r*16 + lc; \
        int sc = (kc*4 + quad) ^ (row & 7); \
        af[r] = *(const v8bf*)(la + row*128 + sc*16); \
      } \
      _Pragma("unroll") \
      for (int c = 0; c < 4; ++c) { \
        int row = wn*64 + c*16 + lc; \
        int sc = (kc*4 + quad) ^ (row & 7); \
        bfr[c] = *(const v8bf*)(lb + row*128 + sc*16); \
      } \
      _Pragma("unroll") \
      for (int r = 0; r < 4; ++r) \
        _Pragma("unroll") \
        for (int c = 0; c < 4; ++c) \
          acc[r][c] = __builtin_amdgcn_mfma_f32_16x16x32_bf16(af[r], bfr[c], acc[r][c], 0, 0, 0); \
    } \
  }

// templated single-GEMM (EPI: 1 = bias+GELU bf16; 4 = bias + r1 fp32)
template<int EPI>
__global__ __launch_bounds__(256, 3) void gemm_bf16(
    const u16* __restrict__ A, const u16* __restrict__ Bt, void* __restrict__ Cout,
    const float* __restrict__ bias, const float* __restrict__ r1,
    int M, int N, int K)
{
  int tiles_n = N >> 7;
  int bm = blockIdx.x / tiles_n, bn = blockIdx.x % tiles_n;
  int tid = threadIdx.x, wv = tid >> 6, lane = tid & 63, quad = lane >> 4, lc = lane & 15;
  int wm = wv & 1, wn = wv >> 1;
  __shared__ __align__(16) u16 lds_[16384];
  char* la = (char*)lds_;
  char* lb = (char*)lds_ + 16384;
  v4f acc[4][4] = {};

  GEMM_BODY(A, Bt, K)

  #pragma unroll
  for (int r = 0; r < 4; ++r) {
    int grow = bm*128 + wm*64 + r*16 + quad*4;
    #pragma unroll
    for (int c = 0; c < 4; ++c) {
      int gcol = bn*128 + wn*64 + c*16 + lc;
      float bv = bias[gcol];
      #pragma unroll
      for (int i = 0; i < 4; ++i) {
        size_t idx = (size_t)(grow + i) * N + gcol;
        float v = acc[r][c][i] + bv;
        if (EPI == 1) {
          float ge = 0.5f * v * (1.f + erff(v * 0.70710678118654752f));
          ((u16*)Cout)[idx] = f2bf(ge);
        } else {
          ((float*)Cout)[idx] = v + r1[idx];
        }
      }
    }
  }
}

// batched GEMM: fixed M=8192, N=1024, K=1024; 512 blocks per sub-GEMM
// epi: 0 = bf16 out; 2 = bias fp32 out; 5 = bf16 transposed out (Ct[N][M], M=8192)
struct GemmDesc { const u16* A; const u16* Bt; void* C; const float* bias; int epi; };
struct GemmBatch { GemmDesc d[3]; };
__global__ __launch_bounds__(256, 3) void gemm_batched(GemmBatch P)
{
  int sub = blockIdx.x >> 9;
  int blk = blockIdx.x & 511;
  int bm = blk >> 3, bn = blk & 7;
  int tid = threadIdx.x, wv = tid >> 6, lane = tid & 63, quad = lane >> 4, lc = lane & 15;
  int wm = wv & 1, wn = wv >> 1;
  const u16* A  = P.d[sub].A;
  const u16* Bt = P.d[sub].Bt;
  void* Cout    = P.d[sub].C;
  int epi       = P.d[sub].epi;
  __shared__ __align__(16) u16 lds_[16384];
  char* la = (char*)lds_;
  char* lb = (char*)lds_ + 16384;
  v4f acc[4][4] = {};

  GEMM_BODY(A, Bt, 1024)

  #pragma unroll
  for (int r = 0; r < 4; ++r) {
    int grow = bm*128 + wm*64 + r*16 + quad*4;
    #pragma unroll
    for (int c = 0; c < 4; ++c) {
      int gcol = bn*128 + wn*64 + c*16 + lc;
      if (epi == 5) {
        ushort4 o;
        o.x = f2bf(acc[r][c][0]); o.y = f2bf(acc[r][c][1]);
        o.z = f2bf(acc[r][c][2]); o.w = f2bf(acc[r][c][3]);
        *(ushort4*)((u16*)Cout + (size_t)gcol * 8192 + grow) = o;
      } else if (epi == 0) {
        #pragma unroll
        for (int i = 0; i < 4; ++i)
          ((u16*)Cout)[(size_t)(grow + i) * 1024 + gcol] = f2bf(acc[r][c][i]);
      } else {
        float bv = P.d[sub].bias[gcol];
        #pragma unroll
        for (int i = 0; i < 4; ++i)
          ((float*)Cout)[(size_t)(grow + i) * 1024 + gcol] = acc[r][c][i] + bv;
      }
    }
  }
}

// ---------------- Flash attention, transposed-S formulation ----------------
__global__ __launch_bounds__(256, 4) void attn_kernel(
    const u16* __restrict__ Q, const u16* __restrict__ K, const u16* __restrict__ VT,
    u16* __restrict__ O)
{
  int bid = blockIdx.x;
  int qt = bid & 15, h = (bid >> 4) & 15, b = bid >> 8;
  int tid = threadIdx.x, wv = tid >> 6, lane = tid & 63, quad = lane >> 4, lc = lane & 15;

  __shared__ __align__(16) char lds_[32768];
  char* kt_l = lds_;            // K tile [128 kv][64 d], 128B rows, swizzled
  char* vt_l = lds_ + 16384;    // VT tile [64 d][128 kv], 256B rows, swizzled

  const float scale = 0.125f;

  v8bf qf[2];
  {
    int qrow = qt*64 + wv*16 + lc;
    const u16* qp = Q + ((size_t)(b*1024 + qrow) * 1024 + h*64 + quad*8);
    qf[0] = *(const v8bf*)qp;
    qf[1] = *(const v8bf*)(qp + 32);
  }

  float m_i = -1e30f, l_i = 0.f;
  v4f oacc[4] = {};

  for (int it = 0; it < 8; ++it) {
    int kvb = it * 128;
    __syncthreads();
    #pragma unroll
    for (int c0 = 0; c0 < 4; ++c0) {
      int ch = wv*4 + c0;
      int off = ch*1024 + lane*16;
      {
        int row = off >> 7, sc = (off >> 4) & 7, lg = sc ^ (row & 7);
        const u16* g = K + (size_t)(b*1024 + kvb + row) * 1024 + h*64 + lg*8;
        GLL16(g, kt_l + ch*1024);
      }
      {
        int row = off >> 8, sc = (off >> 4) & 15, lg = sc ^ (row & 15);
        const u16* g = VT + (size_t)(h*64 + row) * 8192 + b*1024 + kvb + lg*8;
        GLL16(g, vt_l + ch*1024);
      }
    }
    __syncthreads();

    v4f s[8] = {};
    #pragma unroll
    for (int ct = 0; ct < 8; ++ct) {
      int row = ct*16 + lc;
      #pragma unroll
      for (int kc = 0; kc < 2; ++kc) {
        int sc = (kc*4 + quad) ^ (row & 7);
        v8bf kf = *(const v8bf*)(kt_l + row*128 + sc*16);
        s[ct] = __builtin_amdgcn_mfma_f32_16x16x32_bf16(kf, qf[kc], s[ct], 0, 0, 0);
      }
    }

    float mx = m_i;
    #pragma unroll
    for (int ct = 0; ct < 8; ++ct)
      #pragma unroll
      for (int i = 0; i < 4; ++i) mx = fmaxf(mx, s[ct][i] * scale);
    mx = fmaxf(mx, __shfl_xor(mx, 16));
    mx = fmaxf(mx, __shfl_xor(mx, 32));
    float alpha = __expf(m_i - mx);
    float rs = 0.f;
    #pragma unroll
    for (int ct = 0; ct < 8; ++ct)
      #pragma unroll
      for (int i = 0; i < 4; ++i) {
        float p = __expf(s[ct][i] * scale - mx);
        s[ct][i] = p;
        rs += p;
      }
    rs += __shfl_xor(rs, 16);
    rs += __shfl_xor(rs, 32);
    l_i = l_i * alpha + rs;
    m_i = mx;
    #pragma unroll
    for (int dt = 0; dt < 4; ++dt)
      #pragma unroll
      for (int i = 0; i < 4; ++i) oacc[dt][i] *= alpha;

    #pragma unroll
    for (int ct = 0; ct < 8; ++ct) {
      v4s pfrag;
      #pragma unroll
      for (int i = 0; i < 4; ++i) pfrag[i] = (short)f2bf(s[ct][i]);
      int lg = ct*2 + (quad >> 1);
      int ho = (quad & 1) * 8;
      #pragma unroll
      for (int dt = 0; dt < 4; ++dt) {
        int rowd = dt*16 + lc;
        int sc = lg ^ (rowd & 15);
        v4s vfrag = *(const v4s*)(vt_l + rowd*256 + sc*16 + ho);
        oacc[dt] = __builtin_amdgcn_mfma_f32_16x16x16bf16_1k(vfrag, pfrag, oacc[dt], 0, 0, 0);
      }
    }
  }

  __syncthreads();
  {
    char* base = kt_l + wv*2048;
    float inv = 1.f / l_i;
    #pragma unroll
    for (int dt = 0; dt < 4; ++dt) {
      ushort4 o;
      o.x = f2bf(oacc[dt][0]*inv); o.y = f2bf(oacc[dt][1]*inv);
      o.z = f2bf(oacc[dt][2]*inv); o.w = f2bf(oacc[dt][3]*inv);
      int lg = dt*2 + (quad >> 1);
      int sc = lg ^ (lc & 7);
      *(ushort4*)(base + lc*128 + sc*16 + (quad & 1)*8) = o;
    }
  }
  __syncthreads();
  {
    char* base = kt_l + wv*2048;
    #pragma unroll
    for (int rep = 0; rep < 2; ++rep) {
      int qr = rep*8 + (lane >> 3);
      int ch = lane & 7;
      int sc = ch ^ (qr & 7);
      uint4 d = *(const uint4*)(base + qr*128 + sc*16);
      *(uint4*)(O + (size_t)(b*1024 + qt*64 + wv*16 + qr) * 1024 + h*64 + ch*8) = d;
    }
  }
}

// ---------------- host ----------------
extern "C" void kernel_launch(void* const* d_in, const int* in_sizes, int n_in,
                              void* d_out, int out_size, void* d_ws, size_t ws_size,
                              hipStream_t stream)
{
  const float* x1    = (const float*)d_in[0];
  const float* x2    = (const float*)d_in[1];
  const float* x3    = (const float*)d_in[2];
  const float* ln11g = (const float*)d_in[3];
  const float* ln11b = (const float*)d_in[4];
  const float* ln12g = (const float*)d_in[5];
  const float* ln12b = (const float*)d_in[6];
  const float* ln21g = (const float*)d_in[7];
  const float* ln21b = (const float*)d_in[8];
  const float* ln23g = (const float*)d_in[9];
  const float* ln23b = (const float*)d_in[10];
  const float* ln2g  = (const float*)d_in[11];
  const float* ln2b  = (const float*)d_in[12];
  const float* a1wq  = (const float*)d_in[13];
  const float* a1wk  = (const float*)d_in[14];
  const float* a1wv  = (const float*)d_in[15];
  const float* a1wp  = (const float*)d_in[16];
  const float* a1bp  = (const float*)d_in[17];
  const float* a2wq  = (const float*)d_in[18];
  const float* a2wk  = (const float*)d_in[19];
  const float* a2wv  = (const float*)d_in[20];
  const float* a2wp  = (const float*)d_in[21];
  const float* a2bp  = (const float*)d_in[22];
  const float* fc1w  = (const float*)d_in[23];
  const float* fc1b  = (const float*)d_in[24];
  const float* fc2w  = (const float*)d_in[25];
  const float* fc2b  = (const float*)d_in[26];

  char* ws = (char*)d_ws;
  const size_t MB = (size_t)1 << 20;
  // weight transposes (persistent)
  u16* wtq1 = (u16*)(ws + 0*MB);  u16* wtk1 = (u16*)(ws + 2*MB);
  u16* wtv1 = (u16*)(ws + 4*MB);  u16* wtp1 = (u16*)(ws + 6*MB);
  u16* wtq2 = (u16*)(ws + 8*MB);  u16* wtk2 = (u16*)(ws + 10*MB);
  u16* wtv2 = (u16*)(ws + 12*MB); u16* wtp2 = (u16*)(ws + 14*MB);
  u16* wtf1 = (u16*)(ws + 16*MB); u16* wtf2 = (u16*)(ws + 24*MB);
  // activations (liveness-overlapped)
  u16* xq1   = (u16*)(ws + 32*MB);  u16* xkv1 = (u16*)(ws + 48*MB);
  u16* xq2   = (u16*)(ws + 64*MB);  u16* xkv2 = (u16*)(ws + 80*MB);
  u16* Qb    = (u16*)(ws + 96*MB);  u16* Kb   = (u16*)(ws + 112*MB);
  u16* VTb   = (u16*)(ws + 128*MB);
  u16* O1    = (u16*)(ws + 32*MB);                 // over xq1
  u16* O2    = (u16*)(ws + 48*MB);                 // over xkv1
  float* o1f = (float*)(ws + 64*MB);               // over xq2/xkv2
  float* o2f = (float*)(ws + 96*MB);               // over Qb/Kb
  u16* ln2o  = (u16*)(ws + 32*MB);                 // over O1
  u16* hbuf  = (u16*)(ws + 48*MB);                 // 64MB, over O2/o1f/o2f

  dim3 blk(256);

  // 1) all weight transposes in one dispatch
  TBatch tb;
  const float* Ws[10]  = {a1wq, a1wk, a1wv, a1wp, a2wq, a2wk, a2wv, a2wp, fc1w, fc2w};
  u16* WTs[10]         = {wtq1, wtk1, wtv1, wtp1, wtq2, wtk2, wtv2, wtp2, wtf1, wtf2};
  int Kd[10] = {1024,1024,1024,1024,1024,1024,1024,1024,1024,4096};
  int Nd[10] = {1024,1024,1024,1024,1024,1024,1024,1024,4096,1024};
  int ts = 0;
  for (int i = 0; i < 10; ++i) {
    tb.d[i] = {Ws[i], WTs[i], Kd[i], Nd[i], ts};
    ts += (Kd[i]/32) * (Nd[i]/32);
  }
  transpose_batch<<<ts, blk, 0, stream>>>(tb);   // 16384 blocks

  // 2) all 4 pre-attention LayerNorms in one dispatch
  LnBatch lb;
  lb.x[0]=x1; lb.g[0]=ln11g; lb.b[0]=ln11b; lb.o[0]=xq1;
  lb.x[1]=x2; lb.g[1]=ln12g; lb.b[1]=ln12b; lb.o[1]=xkv1;
  lb.x[2]=x1; lb.g[2]=ln21g; lb.b[2]=ln21b; lb.o[2]=xq2;
  lb.x[3]=x3; lb.g[3]=ln23g; lb.b[3]=ln23b; lb.o[3]=xkv2;
  ln_batch_kernel<<<4*8192, blk, 0, stream>>>(lb);

  // 3) branch-1 Q/K/VT in one batched GEMM dispatch
  GemmBatch g1;
  g1.d[0] = {xq1,  wtq1, Qb,  nullptr, 0};
  g1.d[1] = {xkv1, wtk1, Kb,  nullptr, 0};
  g1.d[2] = {xkv1, wtv1, VTb, nullptr, 5};
  gemm_batched<<<1536, blk, 0, stream>>>(g1);

  // 4) attention 1
  attn_kernel<<<2048, blk, 0, stream>>>(Qb, Kb, VTb, O1);

  // 5) branch-2 Q/K/VT
  GemmBatch g2;
  g2.d[0] = {xq2,  wtq2, Qb,  nullptr, 0};
  g2.d[1] = {xkv2, wtk2, Kb,  nullptr, 0};
  g2.d[2] = {xkv2, wtv2, VTb, nullptr, 5};
  gemm_batched<<<1536, blk, 0, stream>>>(g2);

  // 6) attention 2
  attn_kernel<<<2048, blk, 0, stream>>>(Qb, Kb, VTb, O2);

  // 7) both output projections (fp32 + bias)
  GemmBatch gp;
  gp.d[0] = {O1, wtp1, o1f, a1bp, 2};
  gp.d[1] = {O2, wtp2, o2f, a2bp, 2};
  gp.d[2] = gp.d[0];
  gemm_batched<<<1024, blk, 0, stream>>>(gp);

  // 8) x = x1 + o1 + o2 (fp32 -> d_out) and LN -> bf16
  addln_kernel<<<8192, blk, 0, stream>>>(x1, o1f, o2f, ln2g, ln2b, (float*)d_out, ln2o);

  // 9) fc1 + GELU
  gemm_bf16<1><<<(8192/128)*(4096/128), blk, 0, stream>>>(ln2o, wtf1, hbuf, fc1b, nullptr, 8192, 4096, 1024);

  // 10) fc2 + bias + residual (in-place on d_out)
  gemm_bf16<4><<<(8192/128)*(1024/128), blk, 0, stream>>>(hbuf, wtf2, d_out, fc2b, (const float*)d_out, 8192, 1024, 4096);
}

// Round 4
// 742.561 us; speedup vs baseline: 1.0550x; 1.0550x over previous
//
#include <hip/hip_runtime.h>
#include <hip/hip_bf16.h>
#include <cstdint>

typedef unsigned short u16;
typedef __bf16 v8bf __attribute__((ext_vector_type(8)));
typedef short v4s __attribute__((ext_vector_type(4)));
typedef float v4f __attribute__((ext_vector_type(4)));

__device__ __forceinline__ u16 f2bf(float f) {
  union { float f; uint32_t u; } v; v.f = f;
  return (u16)((v.u + 0x7fffu + ((v.u >> 16) & 1u)) >> 16);
}
__device__ __forceinline__ float bf2f(u16 u) {
  union { uint32_t u; float f; } v; v.u = ((uint32_t)u) << 16; return v.f;
}

// async global->LDS, 16B per lane; LDS dest = wave-uniform base + lane*16
#define GLL16(gsrc, ldst) \
  __builtin_amdgcn_global_load_lds((__attribute__((address_space(1))) void*)(gsrc), \
      (__attribute__((address_space(3))) void*)(ldst), 16, 0, 0)

// XCD-aware tile map: 64 bm-tiles always (M=8192). Each XCD (blk%8) owns a
// contiguous 8-row bm band; co-resident blocks sweep bn in lockstep.
#define TILE_MAP(blk, bm, bn) \
  int bm = ((blk) & 7) * 8 + (((blk) >> 3) & 7); \
  int bn = (blk) >> 6;

// ---------------- GEMM core (128x128 tile, BK=64, XOR-swizzled LDS) ----------------
__device__ __forceinline__ void gemm_core(
    const u16* __restrict__ A, const u16* __restrict__ Bt, int K,
    char* la, char* lb, int bm, int bn, int tid, v4f acc[4][4])
{
  int wv = tid >> 6, lane = tid & 63, quad = lane >> 4, lc = lane & 15;
  int wm = wv & 1, wn = wv >> 1;
  for (int kt = 0; kt < K; kt += 64) {
    __syncthreads();
    #pragma unroll
    for (int c0 = 0; c0 < 4; ++c0) {
      int chunk = wv*4 + c0;
      int off = chunk*1024 + lane*16;
      int row = off >> 7;
      int sc  = (off >> 4) & 7;
      int lg  = sc ^ (row & 7);
      GLL16(A  + (size_t)(bm*128 + row) * K + kt + lg*8, la + chunk*1024);
      GLL16(Bt + (size_t)(bn*128 + row) * K + kt + lg*8, lb + chunk*1024);
    }
    __syncthreads();
    #pragma unroll
    for (int kc = 0; kc < 2; ++kc) {
      v8bf af[4], bfr[4];
      #pragma unroll
      for (int r = 0; r < 4; ++r) {
        int row = wm*64 + r*16 + lc;
        int sc = (kc*4 + quad) ^ (row & 7);
        af[r] = *(const v8bf*)(la + row*128 + sc*16);
      }
      #pragma unroll
      for (int c = 0; c < 4; ++c) {
        int row = wn*64 + c*16 + lc;
        int sc = (kc*4 + quad) ^ (row & 7);
        bfr[c] = *(const v8bf*)(lb + row*128 + sc*16);
      }
      #pragma unroll
      for (int r = 0; r < 4; ++r)
        #pragma unroll
        for (int c = 0; c < 4; ++c)
          acc[r][c] = __builtin_amdgcn_mfma_f32_16x16x32_bf16(af[r], bfr[c], acc[r][c], 0, 0, 0);
    }
  }
}

// ---------------- prep: 10 weight transposes + 4 LayerNorms, one dispatch ----------------
struct TDesc { const float* W; u16* WT; int K, N, tstart; };
struct PrepArgs {
  TDesc d[10];
  const float* lx[4]; const float* lg[4]; const float* lb_[4]; u16* lo[4];
  int ts;  // total transpose blocks
};
__global__ __launch_bounds__(256) void prep_kernel(PrepArgs P)
{
  __shared__ float sh[32*33];
  int tid = threadIdx.x;
  if ((int)blockIdx.x < P.ts) {
    int bi = blockIdx.x;
    int idx = 0;
    #pragma unroll
    for (int i = 1; i < 10; ++i) if (bi >= P.d[i].tstart) idx = i;
    const float* W = P.d[idx].W;
    u16* WT = P.d[idx].WT;
    int K = P.d[idx].K, N = P.d[idx].N;
    int loc = bi - P.d[idx].tstart;
    int tiles_n = N >> 5;
    int bn = loc % tiles_n, bk = loc / tiles_n;
    int tx = tid & 31, ty = tid >> 5;
    #pragma unroll
    for (int j = 0; j < 4; ++j)
      sh[(ty + j*8)*33 + tx] = W[(size_t)(bk*32 + ty + j*8) * N + bn*32 + tx];
    __syncthreads();
    #pragma unroll
    for (int j = 0; j < 4; ++j)
      WT[(size_t)(bn*32 + ty + j*8) * K + bk*32 + tx] = f2bf(sh[tx*33 + ty + j*8]);
  } else {
    int lid = blockIdx.x - P.ts;
    int id = lid >> 13, row = lid & 8191;
    const float4* xr = (const float4*)(P.lx[id] + (size_t)row * 1024);
    float4 v = xr[tid];
    float s = v.x + v.y + v.z + v.w;
    float ss = v.x*v.x + v.y*v.y + v.z*v.z + v.w*v.w;
    for (int d = 1; d < 64; d <<= 1) { s += __shfl_xor(s, d); ss += __shfl_xor(ss, d); }
    int wv = tid >> 6, lane = tid & 63;
    if (lane == 0) { sh[wv] = s; sh[4 + wv] = ss; }
    __syncthreads();
    s  = sh[0] + sh[1] + sh[2] + sh[3];
    ss = sh[4] + sh[5] + sh[6] + sh[7];
    float mean = s * (1.f/1024.f);
    float var  = ss * (1.f/1024.f) - mean*mean;
    float rs = rsqrtf(var + 1e-5f);
    float4 gv = ((const float4*)P.lg[id])[tid];
    float4 bv = ((const float4*)P.lb_[id])[tid];
    ushort4 o;
    o.x = f2bf((v.x-mean)*rs*gv.x + bv.x);
    o.y = f2bf((v.y-mean)*rs*gv.y + bv.y);
    o.z = f2bf((v.z-mean)*rs*gv.z + bv.z);
    o.w = f2bf((v.w-mean)*rs*gv.w + bv.w);
    ((ushort4*)P.lo[id])[(size_t)row*256 + tid] = o;
  }
}

// ---------------- plain LayerNorm: fp32 -> bf16 ----------------
__global__ __launch_bounds__(256) void ln_kernel(
    const float* __restrict__ x, const float* __restrict__ g, const float* __restrict__ bt,
    u16* __restrict__ out)
{
  int row = blockIdx.x, tid = threadIdx.x;
  const float4* xr = (const float4*)(x + (size_t)row * 1024);
  float4 v = xr[tid];
  float s = v.x + v.y + v.z + v.w;
  float ss = v.x*v.x + v.y*v.y + v.z*v.z + v.w*v.w;
  for (int d = 1; d < 64; d <<= 1) { s += __shfl_xor(s, d); ss += __shfl_xor(ss, d); }
  __shared__ float red[8];
  int wv = tid >> 6, lane = tid & 63;
  if (lane == 0) { red[wv] = s; red[4 + wv] = ss; }
  __syncthreads();
  s  = red[0] + red[1] + red[2] + red[3];
  ss = red[4] + red[5] + red[6] + red[7];
  float mean = s * (1.f/1024.f);
  float var  = ss * (1.f/1024.f) - mean*mean;
  float rs = rsqrtf(var + 1e-5f);
  float4 gv = ((const float4*)g)[tid];
  float4 bv = ((const float4*)bt)[tid];
  ushort4 o;
  o.x = f2bf((v.x-mean)*rs*gv.x + bv.x);
  o.y = f2bf((v.y-mean)*rs*gv.y + bv.y);
  o.z = f2bf((v.z-mean)*rs*gv.z + bv.z);
  o.w = f2bf((v.w-mean)*rs*gv.w + bv.w);
  ((ushort4*)out)[(size_t)row*256 + tid] = o;
}

// ---------------- batched QKV GEMM: 3 subs x 512 blocks, N=K=1024 ----------------
// sub 0,1: bf16 out; sub 2: bf16 transposed out (VT[1024][8192])
struct QkvArgs { const u16* A[3]; const u16* Bt[3]; u16* C[3]; };
__global__ __launch_bounds__(256, 3) void gemm_qkv(QkvArgs P)
{
  int sub = blockIdx.x >> 9;
  int local = blockIdx.x & 511;
  TILE_MAP(local, bm, bn)
  int tid = threadIdx.x, wv = tid >> 6, lane = tid & 63, quad = lane >> 4, lc = lane & 15;
  int wm = wv & 1, wn = wv >> 1;
  __shared__ __align__(16) char lds_[32768];
  v4f acc[4][4] = {};
  gemm_core(P.A[sub], P.Bt[sub], 1024, lds_, lds_ + 16384, bm, bn, tid, acc);

  u16* Cout = P.C[sub];
  #pragma unroll
  for (int r = 0; r < 4; ++r) {
    int grow = bm*128 + wm*64 + r*16 + quad*4;
    #pragma unroll
    for (int c = 0; c < 4; ++c) {
      int gcol = bn*128 + wn*64 + c*16 + lc;
      if (sub == 2) {
        ushort4 o;
        o.x = f2bf(acc[r][c][0]); o.y = f2bf(acc[r][c][1]);
        o.z = f2bf(acc[r][c][2]); o.w = f2bf(acc[r][c][3]);
        *(ushort4*)(Cout + (size_t)gcol * 8192 + grow) = o;
      } else {
        #pragma unroll
        for (int i = 0; i < 4; ++i)
          Cout[(size_t)(grow + i) * 1024 + gcol] = f2bf(acc[r][c][i]);
      }
    }
  }
}

// ---------------- Flash attention body (transposed-S formulation) ----------------
__device__ __forceinline__ void attn_body(
    const u16* __restrict__ Q, const u16* __restrict__ K, const u16* __restrict__ VT,
    u16* __restrict__ O, int bid, int tid, char* lds_)
{
  int qt = bid & 15, h = (bid >> 4) & 15, b = bid >> 8;
  int wv = tid >> 6, lane = tid & 63, quad = lane >> 4, lc = lane & 15;
  char* kt_l = lds_;            // K tile [128 kv][64 d], 128B rows, swizzled
  char* vt_l = lds_ + 16384;    // VT tile [64 d][128 kv], 256B rows, swizzled
  const float scale = 0.125f;

  v8bf qf[2];
  {
    int qrow = qt*64 + wv*16 + lc;
    const u16* qp = Q + ((size_t)(b*1024 + qrow) * 1024 + h*64 + quad*8);
    qf[0] = *(const v8bf*)qp;
    qf[1] = *(const v8bf*)(qp + 32);
  }

  float m_i = -1e30f, l_i = 0.f;
  v4f oacc[4] = {};

  for (int it = 0; it < 8; ++it) {
    int kvb = it * 128;
    __syncthreads();
    #pragma unroll
    for (int c0 = 0; c0 < 4; ++c0) {
      int ch = wv*4 + c0;
      int off = ch*1024 + lane*16;
      {
        int row = off >> 7, sc = (off >> 4) & 7, lg = sc ^ (row & 7);
        GLL16(K + (size_t)(b*1024 + kvb + row) * 1024 + h*64 + lg*8, kt_l + ch*1024);
      }
      {
        int row = off >> 8, sc = (off >> 4) & 15, lg = sc ^ (row & 15);
        GLL16(VT + (size_t)(h*64 + row) * 8192 + b*1024 + kvb + lg*8, vt_l + ch*1024);
      }
    }
    __syncthreads();

    v4f s[8] = {};
    #pragma unroll
    for (int ct = 0; ct < 8; ++ct) {
      int row = ct*16 + lc;
      #pragma unroll
      for (int kc = 0; kc < 2; ++kc) {
        int sc = (kc*4 + quad) ^ (row & 7);
        v8bf kf = *(const v8bf*)(kt_l + row*128 + sc*16);
        s[ct] = __builtin_amdgcn_mfma_f32_16x16x32_bf16(kf, qf[kc], s[ct], 0, 0, 0);
      }
    }

    float mx = m_i;
    #pragma unroll
    for (int ct = 0; ct < 8; ++ct)
      #pragma unroll
      for (int i = 0; i < 4; ++i) mx = fmaxf(mx, s[ct][i] * scale);
    mx = fmaxf(mx, __shfl_xor(mx, 16));
    mx = fmaxf(mx, __shfl_xor(mx, 32));
    float alpha = __expf(m_i - mx);
    float rs = 0.f;
    #pragma unroll
    for (int ct = 0; ct < 8; ++ct)
      #pragma unroll
      for (int i = 0; i < 4; ++i) {
        float p = __expf(s[ct][i] * scale - mx);
        s[ct][i] = p;
        rs += p;
      }
    rs += __shfl_xor(rs, 16);
    rs += __shfl_xor(rs, 32);
    l_i = l_i * alpha + rs;
    m_i = mx;
    #pragma unroll
    for (int dt = 0; dt < 4; ++dt)
      #pragma unroll
      for (int i = 0; i < 4; ++i) oacc[dt][i] *= alpha;

    #pragma unroll
    for (int ct = 0; ct < 8; ++ct) {
      v4s pfrag;
      #pragma unroll
      for (int i = 0; i < 4; ++i) pfrag[i] = (short)f2bf(s[ct][i]);
      int lg = ct*2 + (quad >> 1);
      int ho = (quad & 1) * 8;
      #pragma unroll
      for (int dt = 0; dt < 4; ++dt) {
        int rowd = dt*16 + lc;
        int sc = lg ^ (rowd & 15);
        v4s vfrag = *(const v4s*)(vt_l + rowd*256 + sc*16 + ho);
        oacc[dt] = __builtin_amdgcn_mfma_f32_16x16x16bf16_1k(vfrag, pfrag, oacc[dt], 0, 0, 0);
      }
    }
  }

  __syncthreads();
  {
    char* base = kt_l + wv*2048;
    float inv = 1.f / l_i;
    #pragma unroll
    for (int dt = 0; dt < 4; ++dt) {
      ushort4 o;
      o.x = f2bf(oacc[dt][0]*inv); o.y = f2bf(oacc[dt][1]*inv);
      o.z = f2bf(oacc[dt][2]*inv); o.w = f2bf(oacc[dt][3]*inv);
      int lg = dt*2 + (quad >> 1);
      int sc = lg ^ (lc & 7);
      *(ushort4*)(base + lc*128 + sc*16 + (quad & 1)*8) = o;
    }
  }
  __syncthreads();
  {
    char* base = kt_l + wv*2048;
    #pragma unroll
    for (int rep = 0; rep < 2; ++rep) {
      int qr = rep*8 + (lane >> 3);
      int ch = lane & 7;
      int sc = ch ^ (qr & 7);
      uint4 d = *(const uint4*)(base + qr*128 + sc*16);
      *(uint4*)(O + (size_t)(b*1024 + qt*64 + wv*16 + qr) * 1024 + h*64 + ch*8) = d;
    }
  }
}

// standalone attention
__global__ __launch_bounds__(256, 4) void attn_kernel(
    const u16* __restrict__ Q, const u16* __restrict__ K, const u16* __restrict__ VT,
    u16* __restrict__ O)
{
  __shared__ __align__(16) char lds_[32768];
  attn_body(Q, K, VT, O, blockIdx.x, threadIdx.x, lds_);
}

// ---------------- fused attention-2 || proj-1 (bias + bf16 out) ----------------
__global__ __launch_bounds__(256, 3) void attn_proj_kernel(
    const u16* __restrict__ Q, const u16* __restrict__ K, const u16* __restrict__ VT,
    u16* __restrict__ O,
    const u16* __restrict__ GA, const u16* __restrict__ GBt,
    const float* __restrict__ Gbias, u16* __restrict__ GC)
{
  __shared__ __align__(16) char lds_[32768];
  int tid = threadIdx.x;
  if ((int)blockIdx.x < 2048) {
    attn_body(Q, K, VT, O, blockIdx.x, tid, lds_);
  } else {
    int local = blockIdx.x - 2048;
    TILE_MAP(local, bm, bn)
    int wv = tid >> 6, lane = tid & 63, quad = lane >> 4, lc = lane & 15;
    int wm = wv & 1, wn = wv >> 1;
    v4f acc[4][4] = {};
    gemm_core(GA, GBt, 1024, lds_, lds_ + 16384, bm, bn, tid, acc);
    #pragma unroll
    for (int r = 0; r < 4; ++r) {
      int grow = bm*128 + wm*64 + r*16 + quad*4;
      #pragma unroll
      for (int c = 0; c < 4; ++c) {
        int gcol = bn*128 + wn*64 + c*16 + lc;
        float bv = Gbias[gcol];
        #pragma unroll
        for (int i = 0; i < 4; ++i)
          GC[(size_t)(grow + i) * 1024 + gcol] = f2bf(acc[r][c][i] + bv);
      }
    }
  }
}

// ---------------- proj-2 + residual sum: xsum = O2@wp2 + bp2 + x1 + o1 ----------------
__global__ __launch_bounds__(256, 3) void gemm_projadd(
    const u16* __restrict__ A, const u16* __restrict__ Bt,
    const float* __restrict__ bias, const float* __restrict__ x1,
    const u16* __restrict__ o1b, float* __restrict__ xsum)
{
  TILE_MAP((int)blockIdx.x, bm, bn)
  int tid = threadIdx.x, wv = tid >> 6, lane = tid & 63, quad = lane >> 4, lc = lane & 15;
  int wm = wv & 1, wn = wv >> 1;
  __shared__ __align__(16) char lds_[32768];
  v4f acc[4][4] = {};
  gemm_core(A, Bt, 1024, lds_, lds_ + 16384, bm, bn, tid, acc);
  #pragma unroll
  for (int r = 0; r < 4; ++r) {
    int grow = bm*128 + wm*64 + r*16 + quad*4;
    #pragma unroll
    for (int c = 0; c < 4; ++c) {
      int gcol = bn*128 + wn*64 + c*16 + lc;
      float bv = bias[gcol];
      #pragma unroll
      for (int i = 0; i < 4; ++i) {
        size_t idx = (size_t)(grow + i) * 1024 + gcol;
        xsum[idx] = acc[r][c][i] + bv + x1[idx] + bf2f(o1b[idx]);
      }
    }
  }
}

// ---------------- fc1: bias + exact GELU, bf16 out, N=4096 ----------------
__global__ __launch_bounds__(256, 3) void gemm_fc1(
    const u16* __restrict__ A, const u16* __restrict__ Bt,
    const float* __restrict__ bias, u16* __restrict__ C)
{
  TILE_MAP((int)blockIdx.x, bm, bn)
  int tid = threadIdx.x, wv = tid >> 6, lane = tid & 63, quad = lane >> 4, lc = lane & 15;
  int wm = wv & 1, wn = wv >> 1;
  __shared__ __align__(16) char lds_[32768];
  v4f acc[4][4] = {};
  gemm_core(A, Bt, 1024, lds_, lds_ + 16384, bm, bn, tid, acc);
  #pragma unroll
  for (int r = 0; r < 4; ++r) {
    int grow = bm*128 + wm*64 + r*16 + quad*4;
    #pragma unroll
    for (int c = 0; c < 4; ++c) {
      int gcol = bn*128 + wn*64 + c*16 + lc;
      float bv = bias[gcol];
      #pragma unroll
      for (int i = 0; i < 4; ++i) {
        float v = acc[r][c][i] + bv;
        float ge = 0.5f * v * (1.f + erff(v * 0.70710678118654752f));
        C[(size_t)(grow + i) * 4096 + gcol] = f2bf(ge);
      }
    }
  }
}

// ---------------- fc2: bias + residual(fp32), fp32 out, K=4096 ----------------
__global__ __launch_bounds__(256, 3) void gemm_fc2(
    const u16* __restrict__ A, const u16* __restrict__ Bt,
    const float* __restrict__ bias, const float* __restrict__ r1,
    float* __restrict__ C)
{
  TILE_MAP((int)blockIdx.x, bm, bn)
  int tid = threadIdx.x, wv = tid >> 6, lane = tid & 63, quad = lane >> 4, lc = lane & 15;
  int wm = wv & 1, wn = wv >> 1;
  __shared__ __align__(16) char lds_[32768];
  v4f acc[4][4] = {};
  gemm_core(A, Bt, 4096, lds_, lds_ + 16384, bm, bn, tid, acc);
  #pragma unroll
  for (int r = 0; r < 4; ++r) {
    int grow = bm*128 + wm*64 + r*16 + quad*4;
    #pragma unroll
    for (int c = 0; c < 4; ++c) {
      int gcol = bn*128 + wn*64 + c*16 + lc;
      float bv = bias[gcol];
      #pragma unroll
      for (int i = 0; i < 4; ++i) {
        size_t idx = (size_t)(grow + i) * 1024 + gcol;
        C[idx] = acc[r][c][i] + bv + r1[idx];
      }
    }
  }
}

// ---------------- host ----------------
extern "C" void kernel_launch(void* const* d_in, const int* in_sizes, int n_in,
                              void* d_out, int out_size, void* d_ws, size_t ws_size,
                              hipStream_t stream)
{
  const float* x1    = (const float*)d_in[0];
  const float* x2    = (const float*)d_in[1];
  const float* x3    = (const float*)d_in[2];
  const float* ln11g = (const float*)d_in[3];
  const float* ln11b = (const float*)d_in[4];
  const float* ln12g = (const float*)d_in[5];
  const float* ln12b = (const float*)d_in[6];
  const float* ln21g = (const float*)d_in[7];
  const float* ln21b = (const float*)d_in[8];
  const float* ln23g = (const float*)d_in[9];
  const float* ln23b = (const float*)d_in[10];
  const float* ln2g  = (const float*)d_in[11];
  const float* ln2b  = (const float*)d_in[12];
  const float* a1wq  = (const float*)d_in[13];
  const float* a1wk  = (const float*)d_in[14];
  const float* a1wv  = (const float*)d_in[15];
  const float* a1wp  = (const float*)d_in[16];
  const float* a1bp  = (const float*)d_in[17];
  const float* a2wq  = (const float*)d_in[18];
  const float* a2wk  = (const float*)d_in[19];
  const float* a2wv  = (const float*)d_in[20];
  const float* a2wp  = (const float*)d_in[21];
  const float* a2bp  = (const float*)d_in[22];
  const float* fc1w  = (const float*)d_in[23];
  const float* fc1b  = (const float*)d_in[24];
  const float* fc2w  = (const float*)d_in[25];
  const float* fc2b  = (const float*)d_in[26];

  char* ws = (char*)d_ws;
  const size_t MB = (size_t)1 << 20;
  // weights (persistent, 0-32 MB)
  u16* wtq1 = (u16*)(ws + 0*MB);  u16* wtk1 = (u16*)(ws + 2*MB);
  u16* wtv1 = (u16*)(ws + 4*MB);  u16* wtp1 = (u16*)(ws + 6*MB);
  u16* wtq2 = (u16*)(ws + 8*MB);  u16* wtk2 = (u16*)(ws + 10*MB);
  u16* wtv2 = (u16*)(ws + 12*MB); u16* wtp2 = (u16*)(ws + 14*MB);
  u16* wtf1 = (u16*)(ws + 16*MB); u16* wtf2 = (u16*)(ws + 24*MB);
  // activations (liveness-overlapped; peak 144 MB)
  u16* xq1  = (u16*)(ws + 32*MB); u16* xkv1 = (u16*)(ws + 48*MB);
  u16* xq2  = (u16*)(ws + 64*MB); u16* xkv2 = (u16*)(ws + 80*MB);
  u16* Qb   = (u16*)(ws + 96*MB); u16* Kb   = (u16*)(ws + 112*MB);
  u16* VTb  = (u16*)(ws + 128*MB);
  u16* O1   = (u16*)(ws + 32*MB);                 // over xq1 (dead after g1)
  u16* O2   = (u16*)(ws + 48*MB);                 // over xkv1 (dead after g1)
  u16* o1b  = (u16*)(ws + 64*MB);                 // over xq2 (dead after g2), bf16
  float* xsum = (float*)(ws + 112*MB);            // 112-144, over Kb+VTb (dead after attn2)
  u16* ln2o = (u16*)(ws + 32*MB);                 // over O1 (dead after proj1)
  u16* hbuf = (u16*)(ws + 48*MB);                 // 48-112 (all dead by fc1)

  dim3 blk(256);

  // D0: all weight transposes + 4 LNs
  PrepArgs pa;
  const float* Ws[10]  = {a1wq, a1wk, a1wv, a1wp, a2wq, a2wk, a2wv, a2wp, fc1w, fc2w};
  u16* WTs[10]         = {wtq1, wtk1, wtv1, wtp1, wtq2, wtk2, wtv2, wtp2, wtf1, wtf2};
  int Kd[10] = {1024,1024,1024,1024,1024,1024,1024,1024,1024,4096};
  int Nd[10] = {1024,1024,1024,1024,1024,1024,1024,1024,4096,1024};
  int ts = 0;
  for (int i = 0; i < 10; ++i) {
    pa.d[i] = {Ws[i], WTs[i], Kd[i], Nd[i], ts};
    ts += (Kd[i]/32) * (Nd[i]/32);
  }
  pa.ts = ts;   // 16384
  pa.lx[0]=x1; pa.lg[0]=ln11g; pa.lb_[0]=ln11b; pa.lo[0]=xq1;
  pa.lx[1]=x2; pa.lg[1]=ln12g; pa.lb_[1]=ln12b; pa.lo[1]=xkv1;
  pa.lx[2]=x1; pa.lg[2]=ln21g; pa.lb_[2]=ln21b; pa.lo[2]=xq2;
  pa.lx[3]=x3; pa.lg[3]=ln23g; pa.lb_[3]=ln23b; pa.lo[3]=xkv2;
  prep_kernel<<<ts + 32768, blk, 0, stream>>>(pa);

  // D1: branch-1 Q/K/VT
  QkvArgs g1;
  g1.A[0]=xq1;  g1.Bt[0]=wtq1; g1.C[0]=Qb;
  g1.A[1]=xkv1; g1.Bt[1]=wtk1; g1.C[1]=Kb;
  g1.A[2]=xkv1; g1.Bt[2]=wtv1; g1.C[2]=VTb;
  gemm_qkv<<<1536, blk, 0, stream>>>(g1);

  // D2: attention 1
  attn_kernel<<<2048, blk, 0, stream>>>(Qb, Kb, VTb, O1);

  // D3: branch-2 Q/K/VT (reuses Qb/Kb/VTb)
  QkvArgs g2;
  g2.A[0]=xq2;  g2.Bt[0]=wtq2; g2.C[0]=Qb;
  g2.A[1]=xkv2; g2.Bt[1]=wtk2; g2.C[1]=Kb;
  g2.A[2]=xkv2; g2.Bt[2]=wtv2; g2.C[2]=VTb;
  gemm_qkv<<<1536, blk, 0, stream>>>(g2);

  // D4: attention 2  ||  proj-1 (o1 = O1@wp1 + bp1, bf16)
  attn_proj_kernel<<<2048 + 512, blk, 0, stream>>>(Qb, Kb, VTb, O2, O1, wtp1, a1bp, o1b);

  // D5: proj-2 + residual sum -> xsum (fp32)
  gemm_projadd<<<512, blk, 0, stream>>>(O2, wtp2, a2bp, x1, o1b, xsum);

  // D6: LN2 -> bf16
  ln_kernel<<<8192, blk, 0, stream>>>(xsum, ln2g, ln2b, ln2o);

  // D7: fc1 + GELU
  gemm_fc1<<<2048, blk, 0, stream>>>(ln2o, wtf1, fc1b, hbuf);

  // D8: fc2 + bias + residual -> d_out
  gemm_fc2<<<512, blk, 0, stream>>>(hbuf, wtf2, fc2b, xsum, (float*)d_out);
}

// Round 5
// 674.758 us; speedup vs baseline: 1.1610x; 1.1005x over previous
//
#include <hip/hip_runtime.h>
#include <hip/hip_bf16.h>
#include <cstdint>

typedef unsigned short u16;
typedef __bf16 v8bf __attribute__((ext_vector_type(8)));
typedef short v4s __attribute__((ext_vector_type(4)));
typedef float v4f __attribute__((ext_vector_type(4)));

__device__ __forceinline__ u16 f2bf(float f) {
  union { float f; uint32_t u; } v; v.f = f;
  return (u16)((v.u + 0x7fffu + ((v.u >> 16) & 1u)) >> 16);
}
__device__ __forceinline__ float bf2f(u16 u) {
  union { uint32_t u; float f; } v; v.u = ((uint32_t)u) << 16; return v.f;
}

// async global->LDS, 16B per lane; LDS dest = wave-uniform base + lane*16
#define GLL16(gsrc, ldst) \
  __builtin_amdgcn_global_load_lds((__attribute__((address_space(1))) void*)(gsrc), \
      (__attribute__((address_space(3))) void*)(ldst), 16, 0, 0)

// XCD-aware tile map (64 bm-tiles, M=8192): XCD (blk%8) owns a contiguous
// 8-row bm band; co-resident blocks sweep bn in lockstep.
#define TILE_MAP(blk, bm, bn) \
  int bm = ((blk) & 7) * 8 + (((blk) >> 3) & 7); \
  int bn = (blk) >> 6;

// ---------------- GEMM core (128x128 tile, BK=64, XOR-swizzled LDS) ----------------
__device__ __forceinline__ void gemm_core(
    const u16* __restrict__ A, const u16* __restrict__ Bt, int K,
    char* la, char* lb, int bm, int bn, int tid, v4f acc[4][4])
{
  int wv = tid >> 6, lane = tid & 63, quad = lane >> 4, lc = lane & 15;
  int wm = wv & 1, wn = wv >> 1;
  for (int kt = 0; kt < K; kt += 64) {
    __syncthreads();
    #pragma unroll
    for (int c0 = 0; c0 < 4; ++c0) {
      int chunk = wv*4 + c0;
      int off = chunk*1024 + lane*16;
      int row = off >> 7;
      int sc  = (off >> 4) & 7;
      int lg  = sc ^ (row & 7);
      GLL16(A  + (size_t)(bm*128 + row) * K + kt + lg*8, la + chunk*1024);
      GLL16(Bt + (size_t)(bn*128 + row) * K + kt + lg*8, lb + chunk*1024);
    }
    __syncthreads();
    #pragma unroll
    for (int kc = 0; kc < 2; ++kc) {
      v8bf af[4], bfr[4];
      #pragma unroll
      for (int r = 0; r < 4; ++r) {
        int row = wm*64 + r*16 + lc;
        int sc = (kc*4 + quad) ^ (row & 7);
        af[r] = *(const v8bf*)(la + row*128 + sc*16);
      }
      #pragma unroll
      for (int c = 0; c < 4; ++c) {
        int row = wn*64 + c*16 + lc;
        int sc = (kc*4 + quad) ^ (row & 7);
        bfr[c] = *(const v8bf*)(lb + row*128 + sc*16);
      }
      #pragma unroll
      for (int r = 0; r < 4; ++r)
        #pragma unroll
        for (int c = 0; c < 4; ++c)
          acc[r][c] = __builtin_amdgcn_mfma_f32_16x16x32_bf16(af[r], bfr[c], acc[r][c], 0, 0, 0);
    }
  }
}

// ---------------- prep: 10 weight transposes + 4 LayerNorms, one dispatch ----------------
struct TDesc { const float* W; u16* WT; int K, N, tstart; };
struct PrepArgs {
  TDesc d[10];
  const float* lx[4]; const float* lg[4]; const float* lb_[4]; u16* lo[4];
  int ts;  // total transpose blocks
};
__global__ __launch_bounds__(256) void prep_kernel(PrepArgs P)
{
  __shared__ float sh[32*33];
  int tid = threadIdx.x;
  if ((int)blockIdx.x < P.ts) {
    int bi = blockIdx.x;
    int idx = 0;
    #pragma unroll
    for (int i = 1; i < 10; ++i) if (bi >= P.d[i].tstart) idx = i;
    const float* W = P.d[idx].W;
    u16* WT = P.d[idx].WT;
    int K = P.d[idx].K, N = P.d[idx].N;
    int loc = bi - P.d[idx].tstart;
    int tiles_n = N >> 5;
    int bn = loc % tiles_n, bk = loc / tiles_n;
    int tx = tid & 31, ty = tid >> 5;
    #pragma unroll
    for (int j = 0; j < 4; ++j)
      sh[(ty + j*8)*33 + tx] = W[(size_t)(bk*32 + ty + j*8) * N + bn*32 + tx];
    __syncthreads();
    #pragma unroll
    for (int j = 0; j < 4; ++j)
      WT[(size_t)(bn*32 + ty + j*8) * K + bk*32 + tx] = f2bf(sh[tx*33 + ty + j*8]);
  } else {
    int lid = blockIdx.x - P.ts;
    int id = lid >> 13, row = lid & 8191;
    const float4* xr = (const float4*)(P.lx[id] + (size_t)row * 1024);
    float4 v = xr[tid];
    float s = v.x + v.y + v.z + v.w;
    float ss = v.x*v.x + v.y*v.y + v.z*v.z + v.w*v.w;
    for (int d = 1; d < 64; d <<= 1) { s += __shfl_xor(s, d); ss += __shfl_xor(ss, d); }
    int wv = tid >> 6, lane = tid & 63;
    if (lane == 0) { sh[wv] = s; sh[4 + wv] = ss; }
    __syncthreads();
    s  = sh[0] + sh[1] + sh[2] + sh[3];
    ss = sh[4] + sh[5] + sh[6] + sh[7];
    float mean = s * (1.f/1024.f);
    float var  = ss * (1.f/1024.f) - mean*mean;
    float rs = rsqrtf(var + 1e-5f);
    float4 gv = ((const float4*)P.lg[id])[tid];
    float4 bv = ((const float4*)P.lb_[id])[tid];
    ushort4 o;
    o.x = f2bf((v.x-mean)*rs*gv.x + bv.x);
    o.y = f2bf((v.y-mean)*rs*gv.y + bv.y);
    o.z = f2bf((v.z-mean)*rs*gv.z + bv.z);
    o.w = f2bf((v.w-mean)*rs*gv.w + bv.w);
    ((ushort4*)P.lo[id])[(size_t)row*256 + tid] = o;
  }
}

// ---------------- LayerNorm with bf16 input: bf16 row -> bf16 row ----------------
__global__ __launch_bounds__(256) void ln_bf16_kernel(
    const u16* __restrict__ x, const float* __restrict__ g, const float* __restrict__ bt,
    u16* __restrict__ out)
{
  int row = blockIdx.x, tid = threadIdx.x;
  ushort4 xr = ((const ushort4*)x)[(size_t)row*256 + tid];
  float4 v;
  v.x = bf2f(xr.x); v.y = bf2f(xr.y); v.z = bf2f(xr.z); v.w = bf2f(xr.w);
  float s = v.x + v.y + v.z + v.w;
  float ss = v.x*v.x + v.y*v.y + v.z*v.z + v.w*v.w;
  for (int d = 1; d < 64; d <<= 1) { s += __shfl_xor(s, d); ss += __shfl_xor(ss, d); }
  __shared__ float red[8];
  int wv = tid >> 6, lane = tid & 63;
  if (lane == 0) { red[wv] = s; red[4 + wv] = ss; }
  __syncthreads();
  s  = red[0] + red[1] + red[2] + red[3];
  ss = red[4] + red[5] + red[6] + red[7];
  float mean = s * (1.f/1024.f);
  float var  = ss * (1.f/1024.f) - mean*mean;
  float rs = rsqrtf(var + 1e-5f);
  float4 gv = ((const float4*)g)[tid];
  float4 bv = ((const float4*)bt)[tid];
  ushort4 o;
  o.x = f2bf((v.x-mean)*rs*gv.x + bv.x);
  o.y = f2bf((v.y-mean)*rs*gv.y + bv.y);
  o.z = f2bf((v.z-mean)*rs*gv.z + bv.z);
  o.w = f2bf((v.w-mean)*rs*gv.w + bv.w);
  ((ushort4*)out)[(size_t)row*256 + tid] = o;
}

// ---------------- batched QKV GEMM: 3 subs x 512 blocks, N=K=1024 ----------------
struct QkvArgs { const u16* A[3]; const u16* Bt[3]; u16* C[3]; };
__global__ __launch_bounds__(256, 3) void gemm_qkv(QkvArgs P)
{
  int sub = blockIdx.x >> 9;
  int local = blockIdx.x & 511;
  TILE_MAP(local, bm, bn)
  int tid = threadIdx.x, wv = tid >> 6, lane = tid & 63, quad = lane >> 4, lc = lane & 15;
  int wm = wv & 1, wn = wv >> 1;
  __shared__ __align__(16) char lds_[32768];
  v4f acc[4][4] = {};
  gemm_core(P.A[sub], P.Bt[sub], 1024, lds_, lds_ + 16384, bm, bn, tid, acc);

  u16* Cout = P.C[sub];
  #pragma unroll
  for (int r = 0; r < 4; ++r) {
    int grow = bm*128 + wm*64 + r*16 + quad*4;
    #pragma unroll
    for (int c = 0; c < 4; ++c) {
      int gcol = bn*128 + wn*64 + c*16 + lc;
      if (sub == 2) {
        ushort4 o;
        o.x = f2bf(acc[r][c][0]); o.y = f2bf(acc[r][c][1]);
        o.z = f2bf(acc[r][c][2]); o.w = f2bf(acc[r][c][3]);
        *(ushort4*)(Cout + (size_t)gcol * 8192 + grow) = o;
      } else {
        #pragma unroll
        for (int i = 0; i < 4; ++i)
          Cout[(size_t)(grow + i) * 1024 + gcol] = f2bf(acc[r][c][i]);
      }
    }
  }
}

// ---------------- Flash attention body (transposed-S formulation) ----------------
__device__ __forceinline__ void attn_body(
    const u16* __restrict__ Q, const u16* __restrict__ K, const u16* __restrict__ VT,
    u16* __restrict__ O, int bid, int tid, char* lds_)
{
  int qt = bid & 15, h = (bid >> 4) & 15, b = bid >> 8;
  int wv = tid >> 6, lane = tid & 63, quad = lane >> 4, lc = lane & 15;
  char* kt_l = lds_;            // K tile [128 kv][64 d], 128B rows, swizzled
  char* vt_l = lds_ + 16384;    // VT tile [64 d][128 kv], 256B rows, swizzled
  const float scale = 0.125f;

  v8bf qf[2];
  {
    int qrow = qt*64 + wv*16 + lc;
    const u16* qp = Q + ((size_t)(b*1024 + qrow) * 1024 + h*64 + quad*8);
    qf[0] = *(const v8bf*)qp;
    qf[1] = *(const v8bf*)(qp + 32);
  }

  float m_i = -1e30f, l_i = 0.f;
  v4f oacc[4] = {};

  for (int it = 0; it < 8; ++it) {
    int kvb = it * 128;
    __syncthreads();
    #pragma unroll
    for (int c0 = 0; c0 < 4; ++c0) {
      int ch = wv*4 + c0;
      int off = ch*1024 + lane*16;
      {
        int row = off >> 7, sc = (off >> 4) & 7, lg = sc ^ (row & 7);
        GLL16(K + (size_t)(b*1024 + kvb + row) * 1024 + h*64 + lg*8, kt_l + ch*1024);
      }
      {
        int row = off >> 8, sc = (off >> 4) & 15, lg = sc ^ (row & 15);
        GLL16(VT + (size_t)(h*64 + row) * 8192 + b*1024 + kvb + lg*8, vt_l + ch*1024);
      }
    }
    __syncthreads();

    v4f s[8] = {};
    #pragma unroll
    for (int ct = 0; ct < 8; ++ct) {
      int row = ct*16 + lc;
      #pragma unroll
      for (int kc = 0; kc < 2; ++kc) {
        int sc = (kc*4 + quad) ^ (row & 7);
        v8bf kf = *(const v8bf*)(kt_l + row*128 + sc*16);
        s[ct] = __builtin_amdgcn_mfma_f32_16x16x32_bf16(kf, qf[kc], s[ct], 0, 0, 0);
      }
    }

    float mx = m_i;
    #pragma unroll
    for (int ct = 0; ct < 8; ++ct)
      #pragma unroll
      for (int i = 0; i < 4; ++i) mx = fmaxf(mx, s[ct][i] * scale);
    mx = fmaxf(mx, __shfl_xor(mx, 16));
    mx = fmaxf(mx, __shfl_xor(mx, 32));
    float alpha = __expf(m_i - mx);
    float rs = 0.f;
    #pragma unroll
    for (int ct = 0; ct < 8; ++ct)
      #pragma unroll
      for (int i = 0; i < 4; ++i) {
        float p = __expf(s[ct][i] * scale - mx);
        s[ct][i] = p;
        rs += p;
      }
    rs += __shfl_xor(rs, 16);
    rs += __shfl_xor(rs, 32);
    l_i = l_i * alpha + rs;
    m_i = mx;
    #pragma unroll
    for (int dt = 0; dt < 4; ++dt)
      #pragma unroll
      for (int i = 0; i < 4; ++i) oacc[dt][i] *= alpha;

    #pragma unroll
    for (int ct = 0; ct < 8; ++ct) {
      v4s pfrag;
      #pragma unroll
      for (int i = 0; i < 4; ++i) pfrag[i] = (short)f2bf(s[ct][i]);
      int lg = ct*2 + (quad >> 1);
      int ho = (quad & 1) * 8;
      #pragma unroll
      for (int dt = 0; dt < 4; ++dt) {
        int rowd = dt*16 + lc;
        int sc = lg ^ (rowd & 15);
        v4s vfrag = *(const v4s*)(vt_l + rowd*256 + sc*16 + ho);
        oacc[dt] = __builtin_amdgcn_mfma_f32_16x16x16bf16_1k(vfrag, pfrag, oacc[dt], 0, 0, 0);
      }
    }
  }

  __syncthreads();
  {
    char* base = kt_l + wv*2048;
    float inv = 1.f / l_i;
    #pragma unroll
    for (int dt = 0; dt < 4; ++dt) {
      ushort4 o;
      o.x = f2bf(oacc[dt][0]*inv); o.y = f2bf(oacc[dt][1]*inv);
      o.z = f2bf(oacc[dt][2]*inv); o.w = f2bf(oacc[dt][3]*inv);
      int lg = dt*2 + (quad >> 1);
      int sc = lg ^ (lc & 7);
      *(ushort4*)(base + lc*128 + sc*16 + (quad & 1)*8) = o;
    }
  }
  __syncthreads();
  {
    char* base = kt_l + wv*2048;
    #pragma unroll
    for (int rep = 0; rep < 2; ++rep) {
      int qr = rep*8 + (lane >> 3);
      int ch = lane & 7;
      int sc = ch ^ (qr & 7);
      uint4 d = *(const uint4*)(base + qr*128 + sc*16);
      *(uint4*)(O + (size_t)(b*1024 + qt*64 + wv*16 + qr) * 1024 + h*64 + ch*8) = d;
    }
  }
}

// standalone attention
__global__ __launch_bounds__(256, 4) void attn_kernel(
    const u16* __restrict__ Q, const u16* __restrict__ K, const u16* __restrict__ VT,
    u16* __restrict__ O)
{
  __shared__ __align__(16) char lds_[32768];
  attn_body(Q, K, VT, O, blockIdx.x, threadIdx.x, lds_);
}

// ---------------- fused attention-2 || proj-1 (bias + bf16 out) ----------------
__global__ __launch_bounds__(256, 3) void attn_proj_kernel(
    const u16* __restrict__ Q, const u16* __restrict__ K, const u16* __restrict__ VT,
    u16* __restrict__ O,
    const u16* __restrict__ GA, const u16* __restrict__ GBt,
    const float* __restrict__ Gbias, u16* __restrict__ GC)
{
  __shared__ __align__(16) char lds_[32768];
  int tid = threadIdx.x;
  if ((int)blockIdx.x < 2048) {
    attn_body(Q, K, VT, O, blockIdx.x, tid, lds_);
  } else {
    int local = blockIdx.x - 2048;
    TILE_MAP(local, bm, bn)
    int wv = tid >> 6, lane = tid & 63, quad = lane >> 4, lc = lane & 15;
    int wm = wv & 1, wn = wv >> 1;
    v4f acc[4][4] = {};
    gemm_core(GA, GBt, 1024, lds_, lds_ + 16384, bm, bn, tid, acc);
    #pragma unroll
    for (int r = 0; r < 4; ++r) {
      int grow = bm*128 + wm*64 + r*16 + quad*4;
      #pragma unroll
      for (int c = 0; c < 4; ++c) {
        int gcol = bn*128 + wn*64 + c*16 + lc;
        float bv = Gbias[gcol];
        #pragma unroll
        for (int i = 0; i < 4; ++i)
          GC[(size_t)(grow + i) * 1024 + gcol] = f2bf(acc[r][c][i] + bv);
      }
    }
  }
}

// ---------------- proj-2 + residual sum: xsum(bf16) = O2@wp2 + bp2 + x1 + o1 ----------------
__global__ __launch_bounds__(256, 3) void gemm_projadd(
    const u16* __restrict__ A, const u16* __restrict__ Bt,
    const float* __restrict__ bias, const float* __restrict__ x1,
    const u16* __restrict__ o1b, u16* __restrict__ xsum)
{
  TILE_MAP((int)blockIdx.x, bm, bn)
  int tid = threadIdx.x, wv = tid >> 6, lane = tid & 63, quad = lane >> 4, lc = lane & 15;
  int wm = wv & 1, wn = wv >> 1;
  __shared__ __align__(16) char lds_[32768];
  v4f acc[4][4] = {};
  gemm_core(A, Bt, 1024, lds_, lds_ + 16384, bm, bn, tid, acc);
  #pragma unroll
  for (int r = 0; r < 4; ++r) {
    int grow = bm*128 + wm*64 + r*16 + quad*4;
    #pragma unroll
    for (int c = 0; c < 4; ++c) {
      int gcol = bn*128 + wn*64 + c*16 + lc;
      float bv = bias[gcol];
      #pragma unroll
      for (int i = 0; i < 4; ++i) {
        size_t idx = (size_t)(grow + i) * 1024 + gcol;
        xsum[idx] = f2bf(acc[r][c][i] + bv + x1[idx] + bf2f(o1b[idx]));
      }
    }
  }
}

// ---------------- fc1: bias + fast GELU, bf16 out, N=4096 ----------------
// R2-best config: launch_bounds(256,2), linear tile map.
__global__ __launch_bounds__(256, 2) void gemm_fc1(
    const u16* __restrict__ A, const u16* __restrict__ Bt,
    const float* __restrict__ bias, u16* __restrict__ C)
{
  int bm = blockIdx.x >> 5, bn = blockIdx.x & 31;
  int tid = threadIdx.x, wv = tid >> 6, lane = tid & 63, quad = lane >> 4, lc = lane & 15;
  int wm = wv & 1, wn = wv >> 1;
  __shared__ __align__(16) char lds_[32768];
  v4f acc[4][4] = {};
  gemm_core(A, Bt, 1024, lds_, lds_ + 16384, bm, bn, tid, acc);
  #pragma unroll
  for (int r = 0; r < 4; ++r) {
    int grow = bm*128 + wm*64 + r*16 + quad*4;
    #pragma unroll
    for (int c = 0; c < 4; ++c) {
      int gcol = bn*128 + wn*64 + c*16 + lc;
      float bv = bias[gcol];
      #pragma unroll
      for (int i = 0; i < 4; ++i) {
        float v = acc[r][c][i] + bv;
        // tanh-form GELU via hardware exp: gelu = v * t/(t+1), t = e^{2*0.79788456*(v+0.044715 v^3)}
        float u2 = fminf(1.5957691216f * (v + 0.044715f * v * v * v), 80.f);
        float t = __expf(u2);
        float ge = v * t / (t + 1.f);
        C[(size_t)(grow + i) * 4096 + gcol] = f2bf(ge);
      }
    }
  }
}

// ---------------- fc2: bias + residual(bf16), fp32 out, K=4096 ----------------
__global__ __launch_bounds__(256, 3) void gemm_fc2(
    const u16* __restrict__ A, const u16* __restrict__ Bt,
    const float* __restrict__ bias, const u16* __restrict__ r1,
    float* __restrict__ C)
{
  TILE_MAP((int)blockIdx.x, bm, bn)
  int tid = threadIdx.x, wv = tid >> 6, lane = tid & 63, quad = lane >> 4, lc = lane & 15;
  int wm = wv & 1, wn = wv >> 1;
  __shared__ __align__(16) char lds_[32768];
  v4f acc[4][4] = {};
  gemm_core(A, Bt, 4096, lds_, lds_ + 16384, bm, bn, tid, acc);
  #pragma unroll
  for (int r = 0; r < 4; ++r) {
    int grow = bm*128 + wm*64 + r*16 + quad*4;
    #pragma unroll
    for (int c = 0; c < 4; ++c) {
      int gcol = bn*128 + wn*64 + c*16 + lc;
      float bv = bias[gcol];
      #pragma unroll
      for (int i = 0; i < 4; ++i) {
        size_t idx = (size_t)(grow + i) * 1024 + gcol;
        C[idx] = acc[r][c][i] + bv + bf2f(r1[idx]);
      }
    }
  }
}

// ---------------- host ----------------
extern "C" void kernel_launch(void* const* d_in, const int* in_sizes, int n_in,
                              void* d_out, int out_size, void* d_ws, size_t ws_size,
                              hipStream_t stream)
{
  const float* x1    = (const float*)d_in[0];
  const float* x2    = (const float*)d_in[1];
  const float* x3    = (const float*)d_in[2];
  const float* ln11g = (const float*)d_in[3];
  const float* ln11b = (const float*)d_in[4];
  const float* ln12g = (const float*)d_in[5];
  const float* ln12b = (const float*)d_in[6];
  const float* ln21g = (const float*)d_in[7];
  const float* ln21b = (const float*)d_in[8];
  const float* ln23g = (const float*)d_in[9];
  const float* ln23b = (const float*)d_in[10];
  const float* ln2g  = (const float*)d_in[11];
  const float* ln2b  = (const float*)d_in[12];
  const float* a1wq  = (const float*)d_in[13];
  const float* a1wk  = (const float*)d_in[14];
  const float* a1wv  = (const float*)d_in[15];
  const float* a1wp  = (const float*)d_in[16];
  const float* a1bp  = (const float*)d_in[17];
  const float* a2wq  = (const float*)d_in[18];
  const float* a2wk  = (const float*)d_in[19];
  const float* a2wv  = (const float*)d_in[20];
  const float* a2wp  = (const float*)d_in[21];
  const float* a2bp  = (const float*)d_in[22];
  const float* fc1w  = (const float*)d_in[23];
  const float* fc1b  = (const float*)d_in[24];
  const float* fc2w  = (const float*)d_in[25];
  const float* fc2b  = (const float*)d_in[26];

  char* ws = (char*)d_ws;
  const size_t MB = (size_t)1 << 20;
  // weights (persistent, 0-32 MB)
  u16* wtq1 = (u16*)(ws + 0*MB);  u16* wtk1 = (u16*)(ws + 2*MB);
  u16* wtv1 = (u16*)(ws + 4*MB);  u16* wtp1 = (u16*)(ws + 6*MB);
  u16* wtq2 = (u16*)(ws + 8*MB);  u16* wtk2 = (u16*)(ws + 10*MB);
  u16* wtv2 = (u16*)(ws + 12*MB); u16* wtp2 = (u16*)(ws + 14*MB);
  u16* wtf1 = (u16*)(ws + 16*MB); u16* wtf2 = (u16*)(ws + 24*MB);
  // activations (liveness-overlapped; peak 144 MB)
  u16* xq1  = (u16*)(ws + 32*MB); u16* xkv1 = (u16*)(ws + 48*MB);
  u16* xq2  = (u16*)(ws + 64*MB); u16* xkv2 = (u16*)(ws + 80*MB);
  u16* Qb   = (u16*)(ws + 96*MB); u16* Kb   = (u16*)(ws + 112*MB);
  u16* VTb  = (u16*)(ws + 128*MB);
  u16* O1   = (u16*)(ws + 32*MB);                 // over xq1 (dead after g1)
  u16* O2   = (u16*)(ws + 48*MB);                 // over xkv1 (dead after g1)
  u16* o1b  = (u16*)(ws + 64*MB);                 // over xq2 (dead after g2), bf16
  u16* xsum = (u16*)(ws + 112*MB);                // bf16, over Kb (dead after attn2)
  u16* ln2o = (u16*)(ws + 32*MB);                 // over O1 (dead after proj1)
  u16* hbuf = (u16*)(ws + 48*MB);                 // 48-112 (all dead by fc1)

  dim3 blk(256);

  // D0: all weight transposes + 4 LNs
  PrepArgs pa;
  const float* Ws[10]  = {a1wq, a1wk, a1wv, a1wp, a2wq, a2wk, a2wv, a2wp, fc1w, fc2w};
  u16* WTs[10]         = {wtq1, wtk1, wtv1, wtp1, wtq2, wtk2, wtv2, wtp2, wtf1, wtf2};
  int Kd[10] = {1024,1024,1024,1024,1024,1024,1024,1024,1024,4096};
  int Nd[10] = {1024,1024,1024,1024,1024,1024,1024,1024,4096,1024};
  int ts = 0;
  for (int i = 0; i < 10; ++i) {
    pa.d[i] = {Ws[i], WTs[i], Kd[i], Nd[i], ts};
    ts += (Kd[i]/32) * (Nd[i]/32);
  }
  pa.ts = ts;   // 16384
  pa.lx[0]=x1; pa.lg[0]=ln11g; pa.lb_[0]=ln11b; pa.lo[0]=xq1;
  pa.lx[1]=x2; pa.lg[1]=ln12g; pa.lb_[1]=ln12b; pa.lo[1]=xkv1;
  pa.lx[2]=x1; pa.lg[2]=ln21g; pa.lb_[2]=ln21b; pa.lo[2]=xq2;
  pa.lx[3]=x3; pa.lg[3]=ln23g; pa.lb_[3]=ln23b; pa.lo[3]=xkv2;
  prep_kernel<<<ts + 32768, blk, 0, stream>>>(pa);

  // D1: branch-1 Q/K/VT
  QkvArgs g1;
  g1.A[0]=xq1;  g1.Bt[0]=wtq1; g1.C[0]=Qb;
  g1.A[1]=xkv1; g1.Bt[1]=wtk1; g1.C[1]=Kb;
  g1.A[2]=xkv1; g1.Bt[2]=wtv1; g1.C[2]=VTb;
  gemm_qkv<<<1536, blk, 0, stream>>>(g1);

  // D2: attention 1
  attn_kernel<<<2048, blk, 0, stream>>>(Qb, Kb, VTb, O1);

  // D3: branch-2 Q/K/VT (reuses Qb/Kb/VTb)
  QkvArgs g2;
  g2.A[0]=xq2;  g2.Bt[0]=wtq2; g2.C[0]=Qb;
  g2.A[1]=xkv2; g2.Bt[1]=wtk2; g2.C[1]=Kb;
  g2.A[2]=xkv2; g2.Bt[2]=wtv2; g2.C[2]=VTb;
  gemm_qkv<<<1536, blk, 0, stream>>>(g2);

  // D4: attention 2  ||  proj-1 (o1 = O1@wp1 + bp1, bf16)
  attn_proj_kernel<<<2048 + 512, blk, 0, stream>>>(Qb, Kb, VTb, O2, O1, wtp1, a1bp, o1b);

  // D5: proj-2 + residual sum -> xsum (bf16)
  gemm_projadd<<<512, blk, 0, stream>>>(O2, wtp2, a2bp, x1, o1b, xsum);

  // D6: LN2 -> bf16
  ln_bf16_kernel<<<8192, blk, 0, stream>>>(xsum, ln2g, ln2b, ln2o);

  // D7: fc1 + GELU
  gemm_fc1<<<2048, blk, 0, stream>>>(ln2o, wtf1, fc1b, hbuf);

  // D8: fc2 + bias + residual -> d_out (fp32)
  gemm_fc2<<<512, blk, 0, stream>>>(hbuf, wtf2, fc2b, xsum, (float*)d_out);
}